// Round 1
// baseline (420.924 us; speedup 1.0000x reference)
//
#include <hip/hip_runtime.h>

// Problem constants (from the reference)
#define BATCH 16384
#define D0 64
#define D1 128

// One block per segment b. 192 threads = 3 waves:
//   wave 0  (tid 0..63)   : out0[b][d=tid]      = sum_{j in [off0[b],off0[b+1])} table0[idx0[j]][d] * w0[j]
//   waves 1-2 (tid 64..191): out1[b][d=tid-64]  = mean_{j in [off1[b],off1[b+1])} table1[idx1[j]][d]
// Each row gather is a fully coalesced 256B / 512B wave read. idx/off/w addresses
// are wave-uniform -> scalar loads. Plenty of waves (49K) for latency hiding.
__global__ __launch_bounds__(192)
void combine_jagged_kernel(const float* __restrict__ table0,
                           const float* __restrict__ table1,
                           const float* __restrict__ w0,
                           const int* __restrict__ idx0,
                           const int* __restrict__ idx1,
                           const int* __restrict__ off0,
                           const int* __restrict__ off1,
                           float* __restrict__ out) {
    const int b = blockIdx.x;
    const int tid = threadIdx.x;

    if (tid < D0) {
        // feature 0: weighted sum pool, D0=64
        const int d = tid;
        const int s = off0[b];
        const int e = off0[b + 1];
        float acc = 0.0f;
        for (int j = s; j < e; ++j) {
            const long long row = (long long)idx0[j];
            acc += table0[row * D0 + d] * w0[j];
        }
        out[(size_t)b * D0 + d] = acc;   // empty segment -> 0 (patch value)
    } else {
        // feature 1: mean pool, D1=128
        const int d = tid - D0;
        const int s = off1[b];
        const int e = off1[b + 1];
        float acc = 0.0f;
        for (int j = s; j < e; ++j) {
            const long long row = (long long)idx1[j];
            acc += table1[row * D1 + d];
        }
        const int cnt = e - s;
        const float val = (cnt > 0) ? acc / (float)cnt : 0.0f;
        out[(size_t)BATCH * D0 + (size_t)b * D1 + d] = val;
    }
}

extern "C" void kernel_launch(void* const* d_in, const int* in_sizes, int n_in,
                              void* d_out, int out_size, void* d_ws, size_t ws_size,
                              hipStream_t stream) {
    const float* table0 = (const float*)d_in[0];   // [V, 64]
    const float* table1 = (const float*)d_in[1];   // [V, 128]
    const float* w0     = (const float*)d_in[2];   // [T]
    const int*   idx0   = (const int*)d_in[3];     // [T]
    const int*   idx1   = (const int*)d_in[4];     // [T]
    const int*   off0   = (const int*)d_in[5];     // [B+1]
    const int*   off1   = (const int*)d_in[6];     // [B+1]
    float* out = (float*)d_out;                    // [B*64] ++ [B*128]

    combine_jagged_kernel<<<BATCH, 192, 0, stream>>>(
        table0, table1, w0, idx0, idx1, off0, off1, out);
}

// Round 2
// 258.924 us; speedup vs baseline: 1.6257x; 1.6257x over previous
//
#include <hip/hip_runtime.h>

#define BATCH 16384

typedef float f4 __attribute__((ext_vector_type(4)));

// One block per segment b. 192 threads = 3 waves:
//   wave 0 : out0[b][0:64]    = sum_j table0[idx0[j]][:] * w0[j]     (weighted sum)
//   wave 1 : out1[b][0:64]    = mean_j table1[idx1[j]][0:64]
//   wave 2 : out1[b][64:128]  = mean_j table1[idx1[j]][64:128]
// Within a wave: 4 row-groups x 16 lanes; each lane loads a float4 of the row
// (16 lanes x 16B = 64 floats). Group g handles rows s+g, s+g+4, ... and the
// main loop keeps 4 independent row-gathers in flight per group (16/wave),
// fixing the round-1 latency-bound profile (1 load in flight, VALUBusy 3%).
// Final cross-group reduce: shfl_xor by 16 and 32 (register-only).
__global__ __launch_bounds__(192)
void combine_jagged_kernel(const float* __restrict__ table0,
                           const float* __restrict__ table1,
                           const float* __restrict__ w0,
                           const int* __restrict__ idx0,
                           const int* __restrict__ idx1,
                           const int* __restrict__ off0,
                           const int* __restrict__ off1,
                           float* __restrict__ out) {
    const int b    = blockIdx.x;
    const int wave = threadIdx.x >> 6;   // 0,1,2
    const int lane = threadIdx.x & 63;
    const int grp  = lane >> 4;          // row-group 0..3
    const int gl   = lane & 15;          // lane within group

    const float* tab; const int* idx; const int* off; const float* wp;
    int ld, colbase;
    if (wave == 0)      { tab = table0; idx = idx0; off = off0; wp = w0;      ld = 64;  colbase = 0;  }
    else if (wave == 1) { tab = table1; idx = idx1; off = off1; wp = nullptr; ld = 128; colbase = 0;  }
    else                { tab = table1; idx = idx1; off = off1; wp = nullptr; ld = 128; colbase = 64; }

    const int s = off[b];
    const int e = off[b + 1];
    const int col = colbase + gl * 4;

    f4 acc = {0.0f, 0.0f, 0.0f, 0.0f};

    int j = s + grp;
    // main loop: 4 rows in flight per group (16 per wave)
    for (; j + 12 < e; j += 16) {
        const int r0 = idx[j];
        const int r1 = idx[j + 4];
        const int r2 = idx[j + 8];
        const int r3 = idx[j + 12];
        const float a0 = wp ? wp[j]      : 1.0f;
        const float a1 = wp ? wp[j + 4]  : 1.0f;
        const float a2 = wp ? wp[j + 8]  : 1.0f;
        const float a3 = wp ? wp[j + 12] : 1.0f;
        const f4 v0 = *(const f4*)(tab + (size_t)r0 * ld + col);
        const f4 v1 = *(const f4*)(tab + (size_t)r1 * ld + col);
        const f4 v2 = *(const f4*)(tab + (size_t)r2 * ld + col);
        const f4 v3 = *(const f4*)(tab + (size_t)r3 * ld + col);
        acc += v0 * a0;
        acc += v1 * a1;
        acc += v2 * a2;
        acc += v3 * a3;
    }
    // tail: one row at a time per group
    for (; j < e; j += 4) {
        const int r = idx[j];
        const float a = wp ? wp[j] : 1.0f;
        const f4 v = *(const f4*)(tab + (size_t)r * ld + col);
        acc += v * a;
    }

    // reduce across the 4 row-groups: lanes l, l^16, l^32, l^48 hold the same col
    acc.x += __shfl_xor(acc.x, 16, 64);
    acc.y += __shfl_xor(acc.y, 16, 64);
    acc.z += __shfl_xor(acc.z, 16, 64);
    acc.w += __shfl_xor(acc.w, 16, 64);
    acc.x += __shfl_xor(acc.x, 32, 64);
    acc.y += __shfl_xor(acc.y, 32, 64);
    acc.z += __shfl_xor(acc.z, 32, 64);
    acc.w += __shfl_xor(acc.w, 32, 64);

    if (grp == 0) {
        if (wave == 0) {
            *(f4*)(out + (size_t)b * 64 + col) = acc;   // empty segment -> 0
        } else {
            const int cnt = e - s;
            const float inv = (cnt > 0) ? 1.0f / (float)cnt : 0.0f;  // mean; empty -> 0
            acc *= inv;
            *(f4*)(out + (size_t)BATCH * 64 + (size_t)b * 128 + col) = acc;
        }
    }
}

extern "C" void kernel_launch(void* const* d_in, const int* in_sizes, int n_in,
                              void* d_out, int out_size, void* d_ws, size_t ws_size,
                              hipStream_t stream) {
    const float* table0 = (const float*)d_in[0];   // [V, 64]
    const float* table1 = (const float*)d_in[1];   // [V, 128]
    const float* w0     = (const float*)d_in[2];   // [T]
    const int*   idx0   = (const int*)d_in[3];     // [T]
    const int*   idx1   = (const int*)d_in[4];     // [T]
    const int*   off0   = (const int*)d_in[5];     // [B+1]
    const int*   off1   = (const int*)d_in[6];     // [B+1]
    float* out = (float*)d_out;                    // [B*64] ++ [B*128]

    combine_jagged_kernel<<<BATCH, 192, 0, stream>>>(
        table0, table1, w0, idx0, idx1, off0, off1, out);
}